// Round 3
// baseline (1524.225 us; speedup 1.0000x reference)
//
#include <hip/hip_runtime.h>
#include <hip/hip_bf16.h>

// Problem constants
#define TT 4096
#define HH 2048
#define CI 2816        // I
#define EE 8
#define KK 2
#define TKN (TT * KK)  // 8192 assignments
#define TM 128         // M tile
#define BK 64          // K tile
#define MAX_MT (TKN / TM + EE)   // 72 worst-case m-tiles
#define ROWS_PAD (MAX_MT * TM)   // 9216 padded rows

typedef short short8 __attribute__((ext_vector_type(8)));
typedef float floatx4 __attribute__((ext_vector_type(4)));

__device__ __forceinline__ unsigned short f2bf(float f) {
  unsigned u = __float_as_uint(f);
  return (unsigned short)((u + 0x8000u) >> 16);
}

__device__ __forceinline__ void cvt_store8(unsigned short* dst, float4 a, float4 b) {
  short8 v;
  v[0] = (short)f2bf(a.x); v[1] = (short)f2bf(a.y);
  v[2] = (short)f2bf(a.z); v[3] = (short)f2bf(a.w);
  v[4] = (short)f2bf(b.x); v[5] = (short)f2bf(b.y);
  v[6] = (short)f2bf(b.z); v[7] = (short)f2bf(b.w);
  *(short8*)dst = v;
}

// async global->LDS, 16B per lane; lds dest = wave-uniform base + lane*16
__device__ __forceinline__ void gload_lds16(const unsigned short* g, unsigned short* l) {
  __builtin_amdgcn_global_load_lds(
      (const __attribute__((address_space(1))) unsigned int*)g,
      (__attribute__((address_space(3))) unsigned int*)l, 16, 0, 0);
}

// XOR-swizzled fragment read: chunk c of logical row r lives at chunk c^(r&7).
// All 8 chunks (32 banks) active for any wave-wide b128 read.
__device__ __forceinline__ short8 lds_frag(const unsigned short (*tile)[BK], int row, int chunk) {
  return *(const short8*)&tile[row][((chunk ^ (row & 7)) << 3)];
}

// ---------------------------------------------------------------------------
// fp32 -> bf16 bulk convert (8 elements/thread, grid-stride)
// ---------------------------------------------------------------------------
__global__ void cvt_kernel(const float* __restrict__ src, unsigned short* __restrict__ dst,
                           int n8) {
  for (int i = blockIdx.x * blockDim.x + threadIdx.x; i < n8; i += gridDim.x * blockDim.x) {
    float4 a = ((const float4*)src)[2 * i];
    float4 b = ((const float4*)src)[2 * i + 1];
    cvt_store8(dst + (size_t)i * 8, a, b);
  }
}

// ---------------------------------------------------------------------------
// bucket tokens by expert into padded TM-row regions
// ---------------------------------------------------------------------------
__global__ void bucket_kernel(const int* __restrict__ ids, const float* __restrict__ tw,
                              int* __restrict__ hdr, int* __restrict__ tok,
                              float* __restrict__ wt) {
  __shared__ int cnt[EE];
  __shared__ int cur[EE];
  int tid = threadIdx.x;
  if (tid < EE) cnt[tid] = 0;
  __syncthreads();
  for (int p = tid; p < TKN; p += 256) atomicAdd(&cnt[ids[p]], 1);
  for (int r = tid; r < ROWS_PAD; r += 256) { tok[r] = 0; wt[r] = 0.f; }
  __syncthreads();
  if (tid == 0) {
    int rb = 0, tb = 0;
    for (int e = 0; e < EE; e++) {
      cur[e] = rb;
      int nt = (cnt[e] + TM - 1) / TM;
      for (int j = 0; j < nt; j++) hdr[1 + tb + j] = e;
      rb += nt * TM;
      tb += nt;
    }
    for (int m = tb; m < MAX_MT; m++) hdr[1 + m] = 0;
    hdr[0] = tb;
  }
  __syncthreads();
  for (int p = tid; p < TKN; p += 256) {
    int e = ids[p];
    int slot = atomicAdd(&cur[e], 1);
    tok[slot] = p / KK;
    wt[slot] = tw[p];
  }
}

// ---------------------------------------------------------------------------
// GEMM1: act[row, i] = silu(x_row.w_gate[e,i]) * (x_row.w_up[e,i])  (bf16 in)
// 128x128 tile; waves in 2x2: wave (wr,wc) computes A-rows wr*64..+64 against
// gate cols wc*32..+32 AND their matching up cols (B rows 64+wc*32..+32).
// ---------------------------------------------------------------------------
__global__ __launch_bounds__(256, 4)
void gemm1_kernel(const unsigned short* __restrict__ xb, const unsigned short* __restrict__ w13b,
                  const int* __restrict__ hdr, const int* __restrict__ tok,
                  unsigned short* __restrict__ act) {
  const int mt = blockIdx.x;
  if (mt >= hdr[0]) return;
  const int e = hdr[1 + mt];
  const int bn = blockIdx.y;          // act cols [bn*64, bn*64+64)
  const int row_base = mt * TM;
  const int tid = threadIdx.x;
  const int lane = tid & 63;
  const int wave = tid >> 6;
  const int wr = wave & 1;
  const int wc = wave >> 1;

  __shared__ __align__(16) unsigned short As[TM][BK];
  __shared__ __align__(16) unsigned short Bs[TM][BK];

  // staging: wave stages rows wave*32..+32; lane covers row +(lane>>3), swizzled chunk
  const int kcol = (((lane & 7) ^ (lane >> 3)) * 8);
  const unsigned short* gA[4];
  const unsigned short* gB[4];
  unsigned short* lA[4];
  unsigned short* lB[4];
#pragma unroll
  for (int j = 0; j < 4; j++) {
    int r = wave * 32 + j * 8 + (lane >> 3);
    gA[j] = xb + (size_t)tok[row_base + r] * HH + kcol;
    int wrow = (r < 64) ? (bn * 64 + r) : (CI + bn * 64 + (r - 64));
    gB[j] = w13b + ((size_t)e * (2 * CI) + wrow) * HH + kcol;
    lA[j] = &As[wave * 32 + j * 8][0];   // wave-uniform
    lB[j] = &Bs[wave * 32 + j * 8][0];
  }

  floatx4 acc[4][4];
#pragma unroll
  for (int mi = 0; mi < 4; mi++)
#pragma unroll
    for (int ci = 0; ci < 4; ci++) acc[mi][ci] = (floatx4){0.f, 0.f, 0.f, 0.f};

  const int lrow = lane & 15;
  const int quad = lane >> 4;

  for (int k0 = 0; k0 < HH; k0 += BK) {
    __syncthreads();
#pragma unroll
    for (int j = 0; j < 4; j++) {
      gload_lds16(gA[j] + k0, lA[j]);
      gload_lds16(gB[j] + k0, lB[j]);
    }
    __syncthreads();
#pragma unroll
    for (int kh = 0; kh < 2; kh++) {
      const int chunk = kh * 4 + quad;
      short8 a[4], b[4];
#pragma unroll
      for (int mi = 0; mi < 4; mi++) a[mi] = lds_frag(As, wr * 64 + mi * 16 + lrow, chunk);
      b[0] = lds_frag(Bs, wc * 32 + lrow, chunk);            // gate frag 0
      b[1] = lds_frag(Bs, wc * 32 + 16 + lrow, chunk);       // gate frag 1
      b[2] = lds_frag(Bs, 64 + wc * 32 + lrow, chunk);       // up frag 0
      b[3] = lds_frag(Bs, 64 + wc * 32 + 16 + lrow, chunk);  // up frag 1
#pragma unroll
      for (int mi = 0; mi < 4; mi++)
#pragma unroll
        for (int ci = 0; ci < 4; ci++)
          acc[mi][ci] = __builtin_amdgcn_mfma_f32_16x16x32_bf16(a[mi], b[ci], acc[mi][ci], 0, 0, 0);
    }
  }

  // cols 0..1 of frag-grid are gate, 2..3 are up (same lane mapping) -> silu*up
#pragma unroll
  for (int mi = 0; mi < 4; mi++) {
#pragma unroll
    for (int cg = 0; cg < 2; cg++) {
#pragma unroll
      for (int r = 0; r < 4; r++) {
        float g = acc[mi][cg][r];
        float uu = acc[mi][cg + 2][r];
        float s = g / (1.f + __expf(-g));
        int row = row_base + wr * 64 + mi * 16 + quad * 4 + r;
        int col = bn * 64 + wc * 32 + cg * 16 + lrow;
        act[(size_t)row * CI + col] = f2bf(s * uu);
      }
    }
  }
}

// ---------------------------------------------------------------------------
// GEMM2: y[row,h] = act_row . w2[e,h,:]; out[tok[row],h] += wt[row]*y
// 128x128 tile, 2x2 wave layout.
// ---------------------------------------------------------------------------
__global__ __launch_bounds__(256, 4)
void gemm2_kernel(const unsigned short* __restrict__ act, const unsigned short* __restrict__ w2b,
                  const int* __restrict__ hdr, const int* __restrict__ tok,
                  const float* __restrict__ wt, float* __restrict__ out) {
  const int mt = blockIdx.x;
  if (mt >= hdr[0]) return;
  const int e = hdr[1 + mt];
  const int h0 = blockIdx.y * TM;
  const int row_base = mt * TM;
  const int tid = threadIdx.x;
  const int lane = tid & 63;
  const int wave = tid >> 6;
  const int wr = wave & 1;
  const int wc = wave >> 1;

  __shared__ __align__(16) unsigned short As[TM][BK];
  __shared__ __align__(16) unsigned short Bs[TM][BK];
  __shared__ int tok_s[TM];
  __shared__ float wt_s[TM];

  if (tid < TM) {
    tok_s[tid] = tok[row_base + tid];
    wt_s[tid] = wt[row_base + tid];
  }

  const int kcol = (((lane & 7) ^ (lane >> 3)) * 8);
  const unsigned short* gA[4];
  const unsigned short* gB[4];
  unsigned short* lA[4];
  unsigned short* lB[4];
#pragma unroll
  for (int j = 0; j < 4; j++) {
    int r = wave * 32 + j * 8 + (lane >> 3);
    gA[j] = act + (size_t)(row_base + r) * CI + kcol;
    gB[j] = w2b + ((size_t)e * HH + h0 + r) * CI + kcol;
    lA[j] = &As[wave * 32 + j * 8][0];
    lB[j] = &Bs[wave * 32 + j * 8][0];
  }

  floatx4 acc[4][4];
#pragma unroll
  for (int mi = 0; mi < 4; mi++)
#pragma unroll
    for (int ci = 0; ci < 4; ci++) acc[mi][ci] = (floatx4){0.f, 0.f, 0.f, 0.f};

  const int lrow = lane & 15;
  const int quad = lane >> 4;

  for (int k0 = 0; k0 < CI; k0 += BK) {
    __syncthreads();
#pragma unroll
    for (int j = 0; j < 4; j++) {
      gload_lds16(gA[j] + k0, lA[j]);
      gload_lds16(gB[j] + k0, lB[j]);
    }
    __syncthreads();
#pragma unroll
    for (int kh = 0; kh < 2; kh++) {
      const int chunk = kh * 4 + quad;
      short8 a[4], b[4];
#pragma unroll
      for (int mi = 0; mi < 4; mi++) a[mi] = lds_frag(As, wr * 64 + mi * 16 + lrow, chunk);
#pragma unroll
      for (int ci = 0; ci < 4; ci++) b[ci] = lds_frag(Bs, wc * 64 + ci * 16 + lrow, chunk);
#pragma unroll
      for (int mi = 0; mi < 4; mi++)
#pragma unroll
        for (int ci = 0; ci < 4; ci++)
          acc[mi][ci] = __builtin_amdgcn_mfma_f32_16x16x32_bf16(a[mi], b[ci], acc[mi][ci], 0, 0, 0);
    }
  }

#pragma unroll
  for (int mi = 0; mi < 4; mi++) {
#pragma unroll
    for (int ci = 0; ci < 4; ci++) {
#pragma unroll
      for (int r = 0; r < 4; r++) {
        int lr = wr * 64 + mi * 16 + quad * 4 + r;
        float w = wt_s[lr];
        if (w != 0.f) {
          atomicAdd(out + (size_t)tok_s[lr] * HH + h0 + wc * 64 + ci * 16 + lrow,
                    acc[mi][ci][r] * w);
        }
      }
    }
  }
}

extern "C" void kernel_launch(void* const* d_in, const int* in_sizes, int n_in,
                              void* d_out, int out_size, void* d_ws, size_t ws_size,
                              hipStream_t stream) {
  const float* x   = (const float*)d_in[0];
  const float* w13 = (const float*)d_in[1];
  const float* w2  = (const float*)d_in[2];
  const float* tw  = (const float*)d_in[3];
  const int*   ids = (const int*)d_in[4];
  float* out = (float*)d_out;

  // workspace layout (bytes)
  char* ws = (char*)d_ws;
  int* hdr = (int*)ws;                                      // 512 B
  int* tok = (int*)(ws + 512);                              // 36864 B
  float* wt = (float*)(ws + 512 + ROWS_PAD * 4);            // 36864 B
  unsigned short* act  = (unsigned short*)(ws + 74240);                       // 51,904,512 B
  unsigned short* xb   = (unsigned short*)(ws + 74240 + 51904512ull);         // 16,777,216 B
  unsigned short* w13b = (unsigned short*)(ws + 74240 + 51904512ull + 16777216ull);   // 184,549,376 B
  unsigned short* w2b  = (unsigned short*)(ws + 74240 + 51904512ull + 16777216ull + 184549376ull); // 92,274,688

  hipMemsetAsync(d_out, 0, (size_t)out_size * sizeof(float), stream);
  bucket_kernel<<<1, 256, 0, stream>>>(ids, tw, hdr, tok, wt);
  cvt_kernel<<<2048, 256, 0, stream>>>(x, xb, TT * HH / 8);
  cvt_kernel<<<4096, 256, 0, stream>>>(w13, w13b, EE * 2 * CI * HH / 8);
  cvt_kernel<<<4096, 256, 0, stream>>>(w2, w2b, EE * HH * CI / 8);
  gemm1_kernel<<<dim3(MAX_MT, CI / 64), 256, 0, stream>>>(xb, w13b, hdr, tok, act);
  gemm2_kernel<<<dim3(MAX_MT, HH / TM), 256, 0, stream>>>(act, w2b, hdr, tok, wt, out);
}